// Round 9
// baseline (3379.934 us; speedup 1.0000x reference)
//
#include <hip/hip_runtime.h>

#define NB    8
#define NCIN  256
#define NH    128
#define NW    128
#define NHW   16384      // NH*NW
#define NQKV  192        // 3*T
#define NCOUT 256

// typed address-space pointers for global_load_lds
typedef const __attribute__((address_space(1))) void* gas_ptr;
typedef __attribute__((address_space(3))) void*       las_ptr;
#define GLD_LDS16(gp, lp) \
  __builtin_amdgcn_global_load_lds((gas_ptr)(gp), (las_ptr)(lp), 16, 0, 0)

// ---------------------------------------------------------------------------
// K1: qkv[b][m][n] = sum_k Wq[m][k] * x[b][k][n]   (1x1 conv as panel GEMM)
//
// Journal:
//  r0: A via chunked s_load in FMA stream -> 400us (SMEM serialization).
//  r1: LDS GEMM + launch_bounds(256,3) -> acc spilled (AGPR shuttle +
//      5.5GB scratch), 2.2ms.  BUT: that structure held 16 global-prefetch
//      floats truly-live across the loop -- inflexible demand.
//  r3: LDS GEMM 8mx8n explicit staging, no hints -> 237us.  VGPR=180.
//  r7: scalar-A stream -> 295us (SMEM chunk serialization; SGPRs are for
//      small resident uniforms, not operand streams).
//  r8: B via global_load_lds (no prefetch VGPRs) -> 257us, VGPR STILL 172:
//      the pressure is the compiler's ds_read pipelining depth (flexible),
//      not staging regs.  2 waves/SIMD, VALUBusy 44%.  LDS pipe measured
//      NOT oversubscribed (~62%) -- the bound is latency coverage.
//  r9 (this): r8 + __launch_bounds__(256,4).  Fixed demand ~92 regs
//      (acc 64 + kk frags 16 + addr 12); cap 128 leaves slack, compiler
//      shortens the ds_read pipeline instead of spilling (unlike r1's
//      inflexible case).  Tripwire: WRITE_SIZE must stay 98304 KB.
// ---------------------------------------------------------------------------
#define K1_BK  16

__global__ __launch_bounds__(256, 4) void k1_qkv(
    const float* __restrict__ x, const float* __restrict__ Wq,
    float* __restrict__ qkv)
{
  __shared__ float Bs[2][K1_BK][256];   // 32 KB, linear rows (gld_lds dest)
  __shared__ float As[2][K1_BK][64];    // 8 KB, [k][m]

  const int tid  = threadIdx.x;
  const int b    = blockIdx.x >> 6;          // 64 n-tiles per batch
  const int n0   = (blockIdx.x & 63) << 8;   // *256
  const int m0   = blockIdx.y << 6;          // *64
  const int lane = tid & 63;
  const int wv   = tid >> 6;                 // wave id 0..3

  // B staging: wave wv owns rows 4*wv..4*wv+3 of each k-tile.
  const float* xrow = x + (size_t)b * NCIN * NHW + n0 + lane * 4;

  // A staging: thread -> (m = tid>>2, k-offset (tid&3)*4) of Wq row
  const int am = tid >> 2;
  const int ak = (tid & 3) << 2;
  const float* aP = Wq + ((size_t)(m0 + am) << 8) + ak;

  // compute mapping: 32 n-groups x 8 m-groups
  const int tx = tid & 31;
  const int ty = tid >> 5;

  // ---- prologue: stage tile 0 ----
#pragma unroll
  for (int i = 0; i < 4; ++i) {
    const int r = wv * 4 + i;
    GLD_LDS16(xrow + (size_t)r * NHW, &Bs[0][r][0]);
  }
  {
    const float4 ra0 = *(const float4*)aP;
    As[0][ak + 0][am] = ra0.x;
    As[0][ak + 1][am] = ra0.y;
    As[0][ak + 2][am] = ra0.z;
    As[0][ak + 3][am] = ra0.w;
  }
  __syncthreads();   // drains vmcnt -> tile 0 resident

  float acc[8][8];
#pragma unroll
  for (int i = 0; i < 8; i++)
#pragma unroll
    for (int j = 0; j < 8; j++) acc[i][j] = 0.f;

  int cur = 0;
  for (int t = 0; t < 16; ++t) {
    const int nxt = cur ^ 1;
    float4 ra = {0.f, 0.f, 0.f, 0.f};
    if (t < 15) {
      const int k0 = (t + 1) * K1_BK;
      // async next-B into Bs[nxt]: nxt last read in iter t-1, ordered by
      // that iter's barrier; this iter's end barrier drains vmcnt before
      // anyone reads Bs[nxt].
#pragma unroll
      for (int i = 0; i < 4; ++i) {
        const int r = wv * 4 + i;
        GLD_LDS16(xrow + (size_t)(k0 + r) * NHW, &Bs[nxt][r][0]);
      }
      ra = *(const float4*)(aP + k0);
    }

#pragma unroll
    for (int kk = 0; kk < K1_BK; ++kk) {
      const float4 a0 = *(const float4*)&As[cur][kk][ty * 4];
      const float4 a1 = *(const float4*)&As[cur][kk][32 + ty * 4];
      const float4 b0 = *(const float4*)&Bs[cur][kk][tx * 4];
      const float4 b1 = *(const float4*)&Bs[cur][kk][128 + tx * 4];
      const float a[8]  = {a0.x, a0.y, a0.z, a0.w, a1.x, a1.y, a1.z, a1.w};
      const float bb[8] = {b0.x, b0.y, b0.z, b0.w, b1.x, b1.y, b1.z, b1.w};
#pragma unroll
      for (int i = 0; i < 8; i++)
#pragma unroll
        for (int j = 0; j < 8; j++) acc[i][j] = fmaf(a[i], bb[j], acc[i][j]);
    }

    if (t < 15) {
      As[nxt][ak + 0][am] = ra.x;
      As[nxt][ak + 1][am] = ra.y;
      As[nxt][ak + 2][am] = ra.z;
      As[nxt][ak + 3][am] = ra.w;
      __syncthreads();
      cur = nxt;
    }
  }

  float* outB = qkv + (size_t)b * NQKV * NHW;
#pragma unroll
  for (int i = 0; i < 8; i++) {
    const int m = m0 + ((i < 4) ? (ty * 4 + i) : (32 + ty * 4 + (i - 4)));
    float4 v0 = {acc[i][0], acc[i][1], acc[i][2], acc[i][3]};
    float4 v1 = {acc[i][4], acc[i][5], acc[i][6], acc[i][7]};
    float* r = outB + (size_t)m * NHW + n0;
    *(float4*)(r + tx * 4)       = v0;
    *(float4*)(r + 128 + tx * 4) = v1;
  }
}

// ---------------------------------------------------------------------------
// K2q: kv partial sums for attention groups 0..7 (sourced from qkv).
// (round-3 verified version, unchanged)
// ---------------------------------------------------------------------------
__global__ __launch_bounds__(256, 4) void k2_qkv_kv(
    const float* __restrict__ qkv, float* __restrict__ kvb)
{
  __shared__ float red[4 * 72];
  const int tid = threadIdx.x;
  const int gg  = blockIdx.y;               // 0..7
  const int P0  = blockIdx.x * 2048;
  const int b   = P0 >> 14;
  const int n0  = P0 & (NHW - 1);

  const float* base = qkv + ((size_t)b * NQKV + gg * 24) * NHW + n0 + tid;

  float acc[72];
#pragma unroll
  for (int i = 0; i < 72; i++) acc[i] = 0.f;

  for (int it = 0; it < 8; it++) {
    const int off = it * 256;
    float kk[8], vv[8];
#pragma unroll
    for (int j = 0; j < 8; j++) kk[j] = fmaxf(base[(size_t)(8 + j) * NHW + off], 0.f);
#pragma unroll
    for (int j = 0; j < 8; j++) vv[j] = base[(size_t)(16 + j) * NHW + off];
#pragma unroll
    for (int d = 0; d < 8; d++) {
#pragma unroll
      for (int e = 0; e < 8; e++) acc[d * 9 + e] = fmaf(kk[d], vv[e], acc[d * 9 + e]);
      acc[d * 9 + 8] += kk[d];
    }
  }

  const int wave = tid >> 6, lane = tid & 63;
#pragma unroll
  for (int i = 0; i < 72; i++) {
    float v = acc[i];
    v += __shfl_down(v, 32);
    v += __shfl_down(v, 16);
    v += __shfl_down(v, 8);
    v += __shfl_down(v, 4);
    v += __shfl_down(v, 2);
    v += __shfl_down(v, 1);
    if (lane == 0) red[wave * 72 + i] = v;
  }
  __syncthreads();
  if (tid < 72) {
    float s = red[tid] + red[72 + tid] + red[144 + tid] + red[216 + tid];
    atomicAdd(&kvb[((size_t)b * 16 + gg) * 72 + tid], s);
  }
}

// ---------------------------------------------------------------------------
// K2d: groups 8..15 — stage qkv halo, W_p in LDS, depthwise 3x3, kv partials.
// (round-3 verified version, unchanged)
// ---------------------------------------------------------------------------
#define HALO_W 34
#define HALO_H 18
#define NPOS   (HALO_W * HALO_H)   // 612

__global__ __launch_bounds__(256, 2) void k2_dw(
    const float* __restrict__ qkv, const float* __restrict__ Wp,
    const float* __restrict__ Wd, float* __restrict__ dq,
    float* __restrict__ kvb)
{
  __shared__ float pbuf[24 * NPOS];
  __shared__ float red[4 * 72];

  const int tid  = threadIdx.x;
  const int gg8  = blockIdx.y;            // 0..7  (attention group = 8+gg8)
  const int bt   = blockIdx.x;            // b*32 + tile
  const int b    = bt >> 5;
  const int tile = bt & 31;
  const int ty0  = (tile >> 2) * 16;      // 8 tiles in y
  const int tx0  = (tile & 3) * 32;       // 4 tiles in x

  const float* src = qkv + ((size_t)b * NQKV + gg8 * 24) * NHW;

  for (int idx = tid; idx < 24 * NPOS; idx += 256) {
    const int c = idx / NPOS, pos = idx % NPOS;
    const int hy = pos / HALO_W, hx = pos % HALO_W;
    const int y = ty0 + hy - 1, xx = tx0 + hx - 1;
    float v = 0.f;
    if (y >= 0 && y < NH && xx >= 0 && xx < NW) v = src[(size_t)c * NHW + y * NW + xx];
    pbuf[idx] = v;
  }
  __syncthreads();

  for (int t = tid; t < 3 * NPOS; t += 256) {
    const int gloc = t / NPOS, pos = t % NPOS;
    float qv[8];
#pragma unroll
    for (int i = 0; i < 8; i++) qv[i] = pbuf[(gloc * 8 + i) * NPOS + pos];
    const float* wp = Wp + (size_t)(gg8 * 3 + gloc) * 64;
#pragma unroll
    for (int o = 0; o < 8; o++) {
      float s = 0.f;
#pragma unroll
      for (int i = 0; i < 8; i++) s = fmaf(wp[o * 8 + i], qv[i], s);
      pbuf[(gloc * 8 + o) * NPOS + pos] = s;
    }
  }
  __syncthreads();

  float acc[72];
#pragma unroll
  for (int i = 0; i < 72; i++) acc[i] = 0.f;

  const float* wdb = Wd + (size_t)gg8 * 24 * 9;

  for (int pp = tid; pp < 512; pp += 256) {
    const int ty = pp >> 5, tx = pp & 31;
    const int n  = (ty0 + ty) * NW + (tx0 + tx);
    float kk[8], vv[8];
#pragma unroll
    for (int cc = 0; cc < 24; cc++) {
      const float* pb = pbuf + cc * NPOS + ty * HALO_W + tx;
      const float* w  = wdb + cc * 9;
      float s = 0.f;
      s = fmaf(w[0], pb[0], s);
      s = fmaf(w[1], pb[1], s);
      s = fmaf(w[2], pb[2], s);
      s = fmaf(w[3], pb[HALO_W + 0], s);
      s = fmaf(w[4], pb[HALO_W + 1], s);
      s = fmaf(w[5], pb[HALO_W + 2], s);
      s = fmaf(w[6], pb[2 * HALO_W + 0], s);
      s = fmaf(w[7], pb[2 * HALO_W + 1], s);
      s = fmaf(w[8], pb[2 * HALO_W + 2], s);
      if (cc < 8) {
        dq[((size_t)b * 64 + gg8 * 8 + cc) * NHW + n] = fmaxf(s, 0.f);
      } else if (cc < 16) {
        kk[cc - 8] = fmaxf(s, 0.f);
      } else {
        vv[cc - 16] = s;
      }
    }
#pragma unroll
    for (int d = 0; d < 8; d++) {
#pragma unroll
      for (int e = 0; e < 8; e++) acc[d * 9 + e] = fmaf(kk[d], vv[e], acc[d * 9 + e]);
      acc[d * 9 + 8] += kk[d];
    }
  }

  const int wave = tid >> 6, lane = tid & 63;
#pragma unroll
  for (int i = 0; i < 72; i++) {
    float v = acc[i];
    v += __shfl_down(v, 32);
    v += __shfl_down(v, 16);
    v += __shfl_down(v, 8);
    v += __shfl_down(v, 4);
    v += __shfl_down(v, 2);
    v += __shfl_down(v, 1);
    if (lane == 0) red[wave * 72 + i] = v;
  }
  __syncthreads();
  if (tid < 72) {
    float s = red[tid] + red[72 + tid] + red[144 + tid] + red[216 + tid];
    atomicAdd(&kvb[((size_t)b * 16 + (8 + gg8)) * 72 + tid], s);
  }
}

// ---------------------------------------------------------------------------
// K3: per pixel: q (16 groups x 8) -> o = (q . kv)[:8] / (q . kv)[8]
//     then y = Wffn @ o, BN affine.  (round-3 verified version, unchanged)
// ---------------------------------------------------------------------------
__global__ __launch_bounds__(256) void k3_attn_ffn(
    const float* __restrict__ qkv, const float* __restrict__ dq,
    const float* __restrict__ kvb, const float* __restrict__ Wf,
    const float* __restrict__ gamma, const float* __restrict__ beta,
    const float* __restrict__ mean, const float* __restrict__ var,
    float* __restrict__ out)
{
  __shared__ float wS[64 * 128];        // 32 KB: Wf[m0..m0+63][0..127]
  __shared__ float oS[2][8][256];       // 16 KB: double-buffered o8 per pixel

  const int tid = threadIdx.x;
  const int b   = blockIdx.x >> 6;          // 64 blocks per batch
  const int n0  = (blockIdx.x & 63) << 8;   // 256 pixels per block
  const int m0  = blockIdx.y << 6;          // 64 out-channels per y-tile
  const int tx  = tid & 63;
  const int ty  = tid >> 6;                 // wave id: m-subgroup

  {
    const float* wsrc = Wf + (size_t)m0 * 128;
#pragma unroll
    for (int i = 0; i < 8; ++i) {
      const int off = i * 1024 + tid * 4;
      *(float4*)&wS[off] = *(const float4*)&wsrc[off];
    }
  }

  float acc[16][4];
#pragma unroll
  for (int m = 0; m < 16; ++m)
#pragma unroll
    for (int p = 0; p < 4; ++p) acc[m][p] = 0.f;

  const float* kvB = kvb + (size_t)b * 16 * 72;

  for (int g = 0; g < 16; ++g) {
    // ---- phase A: this thread computes o8 for pixel (n0 + tid) ----
    const float* qp = (g < 8)
        ? qkv + ((size_t)b * NQKV + g * 24) * NHW + n0 + tid
        : dq  + ((size_t)b * 64 + (g - 8) * 8) * NHW + n0 + tid;
    float qv[8];
#pragma unroll
    for (int j = 0; j < 8; ++j) {
      const float v = qp[(size_t)j * NHW];
      qv[j] = (g < 8) ? fmaxf(v, 0.f) : v;
    }
    const float* kvg = kvB + g * 72;   // uniform -> scalar loads
    float num[9];
#pragma unroll
    for (int e = 0; e < 9; ++e) {
      float s = 0.f;
#pragma unroll
      for (int d = 0; d < 8; ++d) s = fmaf(qv[d], kvg[d * 9 + e], s);
      num[e] = s;
    }
    const float r = __builtin_amdgcn_rcpf(num[8] + 1e-15f);
    const int buf = g & 1;
#pragma unroll
    for (int e = 0; e < 8; ++e) oS[buf][e][tid] = num[e] * r;

    __syncthreads();   // oS[buf] ready (also orders next overwrite of buf^1)

    // ---- phase B: 16 m x 4 px FMAs from LDS ----
    float ov[4][8];
#pragma unroll
    for (int p = 0; p < 4; ++p)
#pragma unroll
      for (int e = 0; e < 8; ++e) ov[p][e] = oS[buf][e][tx + p * 64];

    const float* wrow = &wS[(ty * 16) * 128 + g * 8];
#pragma unroll
    for (int m = 0; m < 16; ++m) {
      const float4 w0 = *(const float4*)&wrow[m * 128];
      const float4 w1 = *(const float4*)&wrow[m * 128 + 4];
      const float w8[8] = {w0.x, w0.y, w0.z, w0.w, w1.x, w1.y, w1.z, w1.w};
#pragma unroll
      for (int p = 0; p < 4; ++p)
#pragma unroll
        for (int e = 0; e < 8; ++e)
          acc[m][p] = fmaf(ov[p][e], w8[e], acc[m][p]);
    }
  }

#pragma unroll
  for (int m = 0; m < 16; ++m) {
    const int oc = m0 + ty * 16 + m;
    const float sc = gamma[oc] * __builtin_amdgcn_rsqf(var[oc] + 1e-5f);
    const float bi = fmaf(-mean[oc], sc, beta[oc]);
    float* op = out + ((size_t)b * NCOUT + oc) * NHW + n0 + tx;
#pragma unroll
    for (int p = 0; p < 4; ++p) op[p * 64] = fmaf(acc[m][p], sc, bi);
  }
}

// ---------------------------------------------------------------------------
extern "C" void kernel_launch(void* const* d_in, const int* in_sizes, int n_in,
                              void* d_out, int out_size, void* d_ws, size_t ws_size,
                              hipStream_t stream) {
  const float* x     = (const float*)d_in[0];
  const float* Wq    = (const float*)d_in[1];
  const float* Wp    = (const float*)d_in[2];
  const float* Wd    = (const float*)d_in[3];
  const float* Wf    = (const float*)d_in[4];
  const float* gamma = (const float*)d_in[5];
  const float* beta  = (const float*)d_in[6];
  const float* mean  = (const float*)d_in[7];
  const float* var   = (const float*)d_in[8];
  float* out = (float*)d_out;

  char* ws = (char*)d_ws;
  float* qkv = (float*)ws;                                   // 8*192*16384*4 = 96 MiB
  float* dq  = (float*)(ws + (size_t)100663296);             // 8*64*16384*4  = 32 MiB
  float* kvb = (float*)(ws + (size_t)134217728);             // 8*16*72*4     = 36 KiB

  hipMemsetAsync(kvb, 0, (size_t)NB * 16 * 72 * sizeof(float), stream);

  k1_qkv<<<dim3(512, 3), 256, 0, stream>>>(x, Wq, qkv);
  k2_qkv_kv<<<dim3(64, 8), 256, 0, stream>>>(qkv, kvb);
  k2_dw<<<dim3(256, 8), 256, 0, stream>>>(qkv, Wp, Wd, dq, kvb);
  k3_attn_ffn<<<dim3(512, 4), 256, 0, stream>>>(qkv, dq, kvb, Wf, gamma, beta,
                                                mean, var, out);
}

// Round 10
// 711.483 us; speedup vs baseline: 4.7505x; 4.7505x over previous
//
#include <hip/hip_runtime.h>

#define NB    8
#define NCIN  256
#define NH    128
#define NW    128
#define NHW   16384      // NH*NW
#define NQKV  192        // 3*T
#define NCOUT 256

// ---------------------------------------------------------------------------
// K1: qkv[b][m][n] = sum_k Wq[m][k] * x[b][k][n]   (1x1 conv as panel GEMM)
//
// Journal (k1):
//  r0: A via chunked s_load in FMA stream -> 400us (SMEM serialization).
//  r1: launch_bounds(256,3) -> acc spill, 5.5GB scratch, 2.2ms.
//  r3: explicit LDS GEMM 8mx8n, no hints -> 237us (best).  VGPR=180 ->
//      2 waves/SIMD, VALUBusy 48%: latency uncovered.
//  r7: scalar-A stream -> 295us (SGPRs are not an operand-stream path).
//  r8: B via global_load_lds -> 257us; VGPR still 172 (pressure is the
//      compiler's ds_read pipelining, not staging regs); +2.36M conflicts.
//  r9: launch_bounds(256,4) -> allocator went to VGPR=64, spilled acc,
//      6.6GB scratch, 2.9ms.  POLICY: no min-waves hints with big
//      accumulators, ever.  Allocator spills rather than de-pipelining.
//  r10 (this): shrink structural demand instead: BN=128, 8m x 4n per
//      thread (acc 32), grid (1024,3).  Same total FMAs, same x-fetch
//      pattern; base demand ~71 regs -> expect natural 100-140 ->
//      3-4 waves/SIMD.  Explicit staging (r3 style), no hints.
// ---------------------------------------------------------------------------
#define K1_BK  16
#define K1_LDB 132      // 128 + 4 pad
#define K1_LDA 64

__global__ __launch_bounds__(256) void k1_qkv(
    const float* __restrict__ x, const float* __restrict__ Wq,
    float* __restrict__ qkv)
{
  __shared__ float Bs[2][K1_BK][K1_LDB];   // 16.5 KB
  __shared__ float As[2][K1_BK][K1_LDA];   // 8 KB

  const int tid = threadIdx.x;
  const int b   = blockIdx.x >> 7;           // 128 n-tiles per batch
  const int n0  = (blockIdx.x & 127) << 7;   // *128
  const int m0  = blockIdx.y << 6;           // *64

  // staging: B -> thread (k-row, 8 cols), A -> thread (m-row, 4 k) transposed
  const int bk = tid >> 4;                   // 0..15
  const int bn = (tid & 15) << 3;            // 0,8,...,120
  const int am = tid >> 2;                   // 0..63
  const int ak = (tid & 3) << 2;             // 0,4,8,12
  const float* bP = x + (size_t)b * NCIN * NHW + (size_t)bk * NHW + n0 + bn;
  const float* aP = Wq + ((size_t)(m0 + am) << 8) + ak;

  // compute mapping: 32 n-groups x 8 m-groups
  const int tx = tid & 31;
  const int ty = tid >> 5;

  float4 rb0, rb1, ra;
  rb0 = *(const float4*)(bP);
  rb1 = *(const float4*)(bP + 4);
  ra  = *(const float4*)(aP);

  *(float4*)&Bs[0][bk][bn]     = rb0;
  *(float4*)&Bs[0][bk][bn + 4] = rb1;
  As[0][ak + 0][am] = ra.x;
  As[0][ak + 1][am] = ra.y;
  As[0][ak + 2][am] = ra.z;
  As[0][ak + 3][am] = ra.w;
  __syncthreads();

  float acc[8][4];
#pragma unroll
  for (int i = 0; i < 8; ++i)
#pragma unroll
    for (int j = 0; j < 4; ++j) acc[i][j] = 0.f;

  int cur = 0;
  for (int t = 0; t < 16; ++t) {
    if (t < 15) {
      const float* bq = bP + (size_t)(t + 1) * K1_BK * NHW;
      rb0 = *(const float4*)(bq);
      rb1 = *(const float4*)(bq + 4);
      ra  = *(const float4*)(aP + (t + 1) * K1_BK);
    }

#pragma unroll
    for (int kk = 0; kk < K1_BK; ++kk) {
      const float4 a0 = *(const float4*)&As[cur][kk][ty * 4];
      const float4 a1 = *(const float4*)&As[cur][kk][32 + ty * 4];
      const float4 bv = *(const float4*)&Bs[cur][kk][tx * 4];
      const float a[8]  = {a0.x, a0.y, a0.z, a0.w, a1.x, a1.y, a1.z, a1.w};
      const float bb[4] = {bv.x, bv.y, bv.z, bv.w};
#pragma unroll
      for (int i = 0; i < 8; ++i)
#pragma unroll
        for (int j = 0; j < 4; ++j) acc[i][j] = fmaf(a[i], bb[j], acc[i][j]);
    }

    if (t < 15) {
      const int nxt = cur ^ 1;
      // safe: Bs/As[nxt] last read in iter t-1, ordered by that barrier
      *(float4*)&Bs[nxt][bk][bn]     = rb0;
      *(float4*)&Bs[nxt][bk][bn + 4] = rb1;
      As[nxt][ak + 0][am] = ra.x;
      As[nxt][ak + 1][am] = ra.y;
      As[nxt][ak + 2][am] = ra.z;
      As[nxt][ak + 3][am] = ra.w;
      __syncthreads();
      cur = nxt;
    }
  }

  float* outB = qkv + (size_t)b * NQKV * NHW + n0 + tx * 4;
#pragma unroll
  for (int i = 0; i < 8; ++i) {
    const int m = m0 + ((i < 4) ? (ty * 4 + i) : (32 + ty * 4 + (i - 4)));
    float4 v = {acc[i][0], acc[i][1], acc[i][2], acc[i][3]};
    *(float4*)(outB + (size_t)m * NHW) = v;
  }
}

// ---------------------------------------------------------------------------
// K2q: kv partial sums for attention groups 0..7 (sourced from qkv).
// (round-3 verified version, unchanged)
// ---------------------------------------------------------------------------
__global__ __launch_bounds__(256, 4) void k2_qkv_kv(
    const float* __restrict__ qkv, float* __restrict__ kvb)
{
  __shared__ float red[4 * 72];
  const int tid = threadIdx.x;
  const int gg  = blockIdx.y;               // 0..7
  const int P0  = blockIdx.x * 2048;
  const int b   = P0 >> 14;
  const int n0  = P0 & (NHW - 1);

  const float* base = qkv + ((size_t)b * NQKV + gg * 24) * NHW + n0 + tid;

  float acc[72];
#pragma unroll
  for (int i = 0; i < 72; i++) acc[i] = 0.f;

  for (int it = 0; it < 8; it++) {
    const int off = it * 256;
    float kk[8], vv[8];
#pragma unroll
    for (int j = 0; j < 8; j++) kk[j] = fmaxf(base[(size_t)(8 + j) * NHW + off], 0.f);
#pragma unroll
    for (int j = 0; j < 8; j++) vv[j] = base[(size_t)(16 + j) * NHW + off];
#pragma unroll
    for (int d = 0; d < 8; d++) {
#pragma unroll
      for (int e = 0; e < 8; e++) acc[d * 9 + e] = fmaf(kk[d], vv[e], acc[d * 9 + e]);
      acc[d * 9 + 8] += kk[d];
    }
  }

  const int wave = tid >> 6, lane = tid & 63;
#pragma unroll
  for (int i = 0; i < 72; i++) {
    float v = acc[i];
    v += __shfl_down(v, 32);
    v += __shfl_down(v, 16);
    v += __shfl_down(v, 8);
    v += __shfl_down(v, 4);
    v += __shfl_down(v, 2);
    v += __shfl_down(v, 1);
    if (lane == 0) red[wave * 72 + i] = v;
  }
  __syncthreads();
  if (tid < 72) {
    float s = red[tid] + red[72 + tid] + red[144 + tid] + red[216 + tid];
    atomicAdd(&kvb[((size_t)b * 16 + gg) * 72 + tid], s);
  }
}

// ---------------------------------------------------------------------------
// K2d: groups 8..15 — stage qkv halo, W_p in LDS, depthwise 3x3, kv partials.
// (round-3 verified version, unchanged)
// ---------------------------------------------------------------------------
#define HALO_W 34
#define HALO_H 18
#define NPOS   (HALO_W * HALO_H)   // 612

__global__ __launch_bounds__(256, 2) void k2_dw(
    const float* __restrict__ qkv, const float* __restrict__ Wp,
    const float* __restrict__ Wd, float* __restrict__ dq,
    float* __restrict__ kvb)
{
  __shared__ float pbuf[24 * NPOS];
  __shared__ float red[4 * 72];

  const int tid  = threadIdx.x;
  const int gg8  = blockIdx.y;            // 0..7  (attention group = 8+gg8)
  const int bt   = blockIdx.x;            // b*32 + tile
  const int b    = bt >> 5;
  const int tile = bt & 31;
  const int ty0  = (tile >> 2) * 16;      // 8 tiles in y
  const int tx0  = (tile & 3) * 32;       // 4 tiles in x

  const float* src = qkv + ((size_t)b * NQKV + gg8 * 24) * NHW;

  for (int idx = tid; idx < 24 * NPOS; idx += 256) {
    const int c = idx / NPOS, pos = idx % NPOS;
    const int hy = pos / HALO_W, hx = pos % HALO_W;
    const int y = ty0 + hy - 1, xx = tx0 + hx - 1;
    float v = 0.f;
    if (y >= 0 && y < NH && xx >= 0 && xx < NW) v = src[(size_t)c * NHW + y * NW + xx];
    pbuf[idx] = v;
  }
  __syncthreads();

  for (int t = tid; t < 3 * NPOS; t += 256) {
    const int gloc = t / NPOS, pos = t % NPOS;
    float qv[8];
#pragma unroll
    for (int i = 0; i < 8; i++) qv[i] = pbuf[(gloc * 8 + i) * NPOS + pos];
    const float* wp = Wp + (size_t)(gg8 * 3 + gloc) * 64;
#pragma unroll
    for (int o = 0; o < 8; o++) {
      float s = 0.f;
#pragma unroll
      for (int i = 0; i < 8; i++) s = fmaf(wp[o * 8 + i], qv[i], s);
      pbuf[(gloc * 8 + o) * NPOS + pos] = s;
    }
  }
  __syncthreads();

  float acc[72];
#pragma unroll
  for (int i = 0; i < 72; i++) acc[i] = 0.f;

  const float* wdb = Wd + (size_t)gg8 * 24 * 9;

  for (int pp = tid; pp < 512; pp += 256) {
    const int ty = pp >> 5, tx = pp & 31;
    const int n  = (ty0 + ty) * NW + (tx0 + tx);
    float kk[8], vv[8];
#pragma unroll
    for (int cc = 0; cc < 24; cc++) {
      const float* pb = pbuf + cc * NPOS + ty * HALO_W + tx;
      const float* w  = wdb + cc * 9;
      float s = 0.f;
      s = fmaf(w[0], pb[0], s);
      s = fmaf(w[1], pb[1], s);
      s = fmaf(w[2], pb[2], s);
      s = fmaf(w[3], pb[HALO_W + 0], s);
      s = fmaf(w[4], pb[HALO_W + 1], s);
      s = fmaf(w[5], pb[HALO_W + 2], s);
      s = fmaf(w[6], pb[2 * HALO_W + 0], s);
      s = fmaf(w[7], pb[2 * HALO_W + 1], s);
      s = fmaf(w[8], pb[2 * HALO_W + 2], s);
      if (cc < 8) {
        dq[((size_t)b * 64 + gg8 * 8 + cc) * NHW + n] = fmaxf(s, 0.f);
      } else if (cc < 16) {
        kk[cc - 8] = fmaxf(s, 0.f);
      } else {
        vv[cc - 16] = s;
      }
    }
#pragma unroll
    for (int d = 0; d < 8; d++) {
#pragma unroll
      for (int e = 0; e < 8; e++) acc[d * 9 + e] = fmaf(kk[d], vv[e], acc[d * 9 + e]);
      acc[d * 9 + 8] += kk[d];
    }
  }

  const int wave = tid >> 6, lane = tid & 63;
#pragma unroll
  for (int i = 0; i < 72; i++) {
    float v = acc[i];
    v += __shfl_down(v, 32);
    v += __shfl_down(v, 16);
    v += __shfl_down(v, 8);
    v += __shfl_down(v, 4);
    v += __shfl_down(v, 2);
    v += __shfl_down(v, 1);
    if (lane == 0) red[wave * 72 + i] = v;
  }
  __syncthreads();
  if (tid < 72) {
    float s = red[tid] + red[72 + tid] + red[144 + tid] + red[216 + tid];
    atomicAdd(&kvb[((size_t)b * 16 + (8 + gg8)) * 72 + tid], s);
  }
}

// ---------------------------------------------------------------------------
// K3: per pixel: q (16 groups x 8) -> o = (q . kv)[:8] / (q . kv)[8]
//     then y = Wffn @ o, BN affine.  (round-3 verified version, unchanged)
// ---------------------------------------------------------------------------
__global__ __launch_bounds__(256) void k3_attn_ffn(
    const float* __restrict__ qkv, const float* __restrict__ dq,
    const float* __restrict__ kvb, const float* __restrict__ Wf,
    const float* __restrict__ gamma, const float* __restrict__ beta,
    const float* __restrict__ mean, const float* __restrict__ var,
    float* __restrict__ out)
{
  __shared__ float wS[64 * 128];        // 32 KB: Wf[m0..m0+63][0..127]
  __shared__ float oS[2][8][256];       // 16 KB: double-buffered o8 per pixel

  const int tid = threadIdx.x;
  const int b   = blockIdx.x >> 6;          // 64 blocks per batch
  const int n0  = (blockIdx.x & 63) << 8;   // 256 pixels per block
  const int m0  = blockIdx.y << 6;          // 64 out-channels per y-tile
  const int tx  = tid & 63;
  const int ty  = tid >> 6;                 // wave id: m-subgroup

  {
    const float* wsrc = Wf + (size_t)m0 * 128;
#pragma unroll
    for (int i = 0; i < 8; ++i) {
      const int off = i * 1024 + tid * 4;
      *(float4*)&wS[off] = *(const float4*)&wsrc[off];
    }
  }

  float acc[16][4];
#pragma unroll
  for (int m = 0; m < 16; ++m)
#pragma unroll
    for (int p = 0; p < 4; ++p) acc[m][p] = 0.f;

  const float* kvB = kvb + (size_t)b * 16 * 72;

  for (int g = 0; g < 16; ++g) {
    // ---- phase A: this thread computes o8 for pixel (n0 + tid) ----
    const float* qp = (g < 8)
        ? qkv + ((size_t)b * NQKV + g * 24) * NHW + n0 + tid
        : dq  + ((size_t)b * 64 + (g - 8) * 8) * NHW + n0 + tid;
    float qv[8];
#pragma unroll
    for (int j = 0; j < 8; ++j) {
      const float v = qp[(size_t)j * NHW];
      qv[j] = (g < 8) ? fmaxf(v, 0.f) : v;
    }
    const float* kvg = kvB + g * 72;   // uniform -> scalar loads
    float num[9];
#pragma unroll
    for (int e = 0; e < 9; ++e) {
      float s = 0.f;
#pragma unroll
      for (int d = 0; d < 8; ++d) s = fmaf(qv[d], kvg[d * 9 + e], s);
      num[e] = s;
    }
    const float r = __builtin_amdgcn_rcpf(num[8] + 1e-15f);
    const int buf = g & 1;
#pragma unroll
    for (int e = 0; e < 8; ++e) oS[buf][e][tid] = num[e] * r;

    __syncthreads();   // oS[buf] ready (also orders next overwrite of buf^1)

    // ---- phase B: 16 m x 4 px FMAs from LDS ----
    float ov[4][8];
#pragma unroll
    for (int p = 0; p < 4; ++p)
#pragma unroll
      for (int e = 0; e < 8; ++e) ov[p][e] = oS[buf][e][tx + p * 64];

    const float* wrow = &wS[(ty * 16) * 128 + g * 8];
#pragma unroll
    for (int m = 0; m < 16; ++m) {
      const float4 w0 = *(const float4*)&wrow[m * 128];
      const float4 w1 = *(const float4*)&wrow[m * 128 + 4];
      const float w8[8] = {w0.x, w0.y, w0.z, w0.w, w1.x, w1.y, w1.z, w1.w};
#pragma unroll
      for (int p = 0; p < 4; ++p)
#pragma unroll
        for (int e = 0; e < 8; ++e)
          acc[m][p] = fmaf(ov[p][e], w8[e], acc[m][p]);
    }
  }

#pragma unroll
  for (int m = 0; m < 16; ++m) {
    const int oc = m0 + ty * 16 + m;
    const float sc = gamma[oc] * __builtin_amdgcn_rsqf(var[oc] + 1e-5f);
    const float bi = fmaf(-mean[oc], sc, beta[oc]);
    float* op = out + ((size_t)b * NCOUT + oc) * NHW + n0 + tx;
#pragma unroll
    for (int p = 0; p < 4; ++p) op[p * 64] = fmaf(acc[m][p], sc, bi);
  }
}

// ---------------------------------------------------------------------------
extern "C" void kernel_launch(void* const* d_in, const int* in_sizes, int n_in,
                              void* d_out, int out_size, void* d_ws, size_t ws_size,
                              hipStream_t stream) {
  const float* x     = (const float*)d_in[0];
  const float* Wq    = (const float*)d_in[1];
  const float* Wp    = (const float*)d_in[2];
  const float* Wd    = (const float*)d_in[3];
  const float* Wf    = (const float*)d_in[4];
  const float* gamma = (const float*)d_in[5];
  const float* beta  = (const float*)d_in[6];
  const float* mean  = (const float*)d_in[7];
  const float* var   = (const float*)d_in[8];
  float* out = (float*)d_out;

  char* ws = (char*)d_ws;
  float* qkv = (float*)ws;                                   // 8*192*16384*4 = 96 MiB
  float* dq  = (float*)(ws + (size_t)100663296);             // 8*64*16384*4  = 32 MiB
  float* kvb = (float*)(ws + (size_t)134217728);             // 8*16*72*4     = 36 KiB

  hipMemsetAsync(kvb, 0, (size_t)NB * 16 * 72 * sizeof(float), stream);

  k1_qkv<<<dim3(1024, 3), 256, 0, stream>>>(x, Wq, qkv);
  k2_qkv_kv<<<dim3(64, 8), 256, 0, stream>>>(qkv, kvb);
  k2_dw<<<dim3(256, 8), 256, 0, stream>>>(qkv, Wp, Wd, dq, kvb);
  k3_attn_ffn<<<dim3(512, 4), 256, 0, stream>>>(qkv, dq, kvb, Wf, gamma, beta,
                                                mean, var, out);
}

// Round 11
// 682.603 us; speedup vs baseline: 4.9515x; 1.0423x over previous
//
#include <hip/hip_runtime.h>

#define NB    8
#define NCIN  256
#define NH    128
#define NW    128
#define NHW   16384      // NH*NW
#define NQKV  192        // 3*T
#define NCOUT 256

// ---------------------------------------------------------------------------
// K1: qkv[b][m][n] = sum_k Wq[m][k] * x[b][k][n]   (1x1 conv as panel GEMM)
// r10 design (verified, fell out of top-5): BN=128, 8m x 4n/thread (acc 32),
// grid (1024,3), explicit double-buffered staging, NO launch-bounds hints
// (r1/r9: min-waves hints spill big accumulators -- permanent policy).
// ---------------------------------------------------------------------------
#define K1_BK  16
#define K1_LDB 132      // 128 + 4 pad
#define K1_LDA 64

__global__ __launch_bounds__(256) void k1_qkv(
    const float* __restrict__ x, const float* __restrict__ Wq,
    float* __restrict__ qkv)
{
  __shared__ float Bs[2][K1_BK][K1_LDB];   // 16.5 KB
  __shared__ float As[2][K1_BK][K1_LDA];   // 8 KB

  const int tid = threadIdx.x;
  const int b   = blockIdx.x >> 7;           // 128 n-tiles per batch
  const int n0  = (blockIdx.x & 127) << 7;   // *128
  const int m0  = blockIdx.y << 6;           // *64

  const int bk = tid >> 4;                   // 0..15
  const int bn = (tid & 15) << 3;            // 0,8,...,120
  const int am = tid >> 2;                   // 0..63
  const int ak = (tid & 3) << 2;             // 0,4,8,12
  const float* bP = x + (size_t)b * NCIN * NHW + (size_t)bk * NHW + n0 + bn;
  const float* aP = Wq + ((size_t)(m0 + am) << 8) + ak;

  const int tx = tid & 31;
  const int ty = tid >> 5;

  float4 rb0, rb1, ra;
  rb0 = *(const float4*)(bP);
  rb1 = *(const float4*)(bP + 4);
  ra  = *(const float4*)(aP);

  *(float4*)&Bs[0][bk][bn]     = rb0;
  *(float4*)&Bs[0][bk][bn + 4] = rb1;
  As[0][ak + 0][am] = ra.x;
  As[0][ak + 1][am] = ra.y;
  As[0][ak + 2][am] = ra.z;
  As[0][ak + 3][am] = ra.w;
  __syncthreads();

  float acc[8][4];
#pragma unroll
  for (int i = 0; i < 8; ++i)
#pragma unroll
    for (int j = 0; j < 4; ++j) acc[i][j] = 0.f;

  int cur = 0;
  for (int t = 0; t < 16; ++t) {
    if (t < 15) {
      const float* bq = bP + (size_t)(t + 1) * K1_BK * NHW;
      rb0 = *(const float4*)(bq);
      rb1 = *(const float4*)(bq + 4);
      ra  = *(const float4*)(aP + (t + 1) * K1_BK);
    }

#pragma unroll
    for (int kk = 0; kk < K1_BK; ++kk) {
      const float4 a0 = *(const float4*)&As[cur][kk][ty * 4];
      const float4 a1 = *(const float4*)&As[cur][kk][32 + ty * 4];
      const float4 bv = *(const float4*)&Bs[cur][kk][tx * 4];
      const float a[8]  = {a0.x, a0.y, a0.z, a0.w, a1.x, a1.y, a1.z, a1.w};
      const float bb[4] = {bv.x, bv.y, bv.z, bv.w};
#pragma unroll
      for (int i = 0; i < 8; ++i)
#pragma unroll
        for (int j = 0; j < 4; ++j) acc[i][j] = fmaf(a[i], bb[j], acc[i][j]);
    }

    if (t < 15) {
      const int nxt = cur ^ 1;
      *(float4*)&Bs[nxt][bk][bn]     = rb0;
      *(float4*)&Bs[nxt][bk][bn + 4] = rb1;
      As[nxt][ak + 0][am] = ra.x;
      As[nxt][ak + 1][am] = ra.y;
      As[nxt][ak + 2][am] = ra.z;
      As[nxt][ak + 3][am] = ra.w;
      __syncthreads();
      cur = nxt;
    }
  }

  float* outB = qkv + (size_t)b * NQKV * NHW + n0 + tx * 4;
#pragma unroll
  for (int i = 0; i < 8; ++i) {
    const int m = m0 + ((i < 4) ? (ty * 4 + i) : (32 + ty * 4 + (i - 4)));
    float4 v = {acc[i][0], acc[i][1], acc[i][2], acc[i][3]};
    *(float4*)(outB + (size_t)m * NHW) = v;
  }
}

// ---------------------------------------------------------------------------
// K2d (round-11 rework): groups 8..15 depthwise path PLUS the raw-kv
// partials for attention groups 0..7 (the old k2_qkv_kv kernel re-read the
// exact channels this kernel stages in LDS -- fused, kernel deleted).
// Phases per block (b, tile, gg8):
//   1  : halo load, fixed-position addressing (1 div/pos, channel loop)
//   1a : kv[b][gg8] partials from RAW relu(k),v in pbuf (pre-W_p) + atomic
//   1b : W_p applied in place (unchanged)
//   2  : depthwise 3x3, pixel-PAIR per thread (shared taps, float2 LDS
//        reads, 3x fewer LDS instrs), dq float2 stores, kv[b][8+gg8] + atomic
// r10 counters: 205us, VALUBusy 25%, Occ 22.7% (LDS-capped 2 blocks/CU),
// 846 GB/s -- latency-bound; attacking addressing VALU + LDS instr count.
// ---------------------------------------------------------------------------
#define HALO_W 34
#define HALO_H 18
#define NPOS   (HALO_W * HALO_H)   // 612

__global__ __launch_bounds__(256, 2) void k2_dw(
    const float* __restrict__ qkv, const float* __restrict__ Wp,
    const float* __restrict__ Wd, float* __restrict__ dq,
    float* __restrict__ kvb)
{
  __shared__ float pbuf[24 * NPOS];
  __shared__ float red[4 * 72];

  const int tid  = threadIdx.x;
  const int gg8  = blockIdx.y;            // 0..7
  const int bt   = blockIdx.x;            // b*32 + tile
  const int b    = bt >> 5;
  const int tile = bt & 31;
  const int ty0  = (tile >> 2) * 16;      // 8 tiles in y
  const int tx0  = (tile & 3) * 32;       // 4 tiles in x

  const float* src = qkv + ((size_t)b * NQKV + gg8 * 24) * NHW;

  // ---- phase 1: halo load (decode position once, loop channels) ----
#pragma unroll
  for (int p = 0; p < 3; ++p) {
    const int pos = tid + p * 256;
    if (pos < NPOS) {
      const int hy = pos / HALO_W;
      const int hx = pos - hy * HALO_W;
      const int y  = ty0 + hy - 1;
      const int xx = tx0 + hx - 1;
      float* dp = pbuf + pos;
      if (y >= 0 && y < NH && xx >= 0 && xx < NW) {
        const float* sp = src + y * NW + xx;
#pragma unroll
        for (int c = 0; c < 24; ++c) dp[c * NPOS] = sp[(size_t)c * NHW];
      } else {
#pragma unroll
        for (int c = 0; c < 24; ++c) dp[c * NPOS] = 0.f;
      }
    }
  }
  __syncthreads();

  const int wave = tid >> 6, lane = tid & 63;
  const int py = tid >> 4;            // 0..15 pixel row
  const int px = (tid & 15) << 1;     // 0..30 even col; thread owns (px, px+1)

  // ---- phase 1a: raw-kv partials for attention group gg8 (was k2_qkv_kv) ----
  {
    const int pos = (py + 1) * HALO_W + (px + 1);
    float k0[8], k1[8], v0[8], v1[8];
#pragma unroll
    for (int j = 0; j < 8; ++j) {
      const float* kp = pbuf + (8 + j) * NPOS + pos;
      k0[j] = fmaxf(kp[0], 0.f);
      k1[j] = fmaxf(kp[1], 0.f);
      const float* vp = pbuf + (16 + j) * NPOS + pos;
      v0[j] = vp[0];
      v1[j] = vp[1];
    }
    float a[72];
#pragma unroll
    for (int d = 0; d < 8; ++d) {
#pragma unroll
      for (int e = 0; e < 8; ++e)
        a[d * 9 + e] = fmaf(k0[d], v0[e], k1[d] * v1[e]);
      a[d * 9 + 8] = k0[d] + k1[d];
    }
#pragma unroll
    for (int i = 0; i < 72; ++i) {
      float v = a[i];
      v += __shfl_down(v, 32);
      v += __shfl_down(v, 16);
      v += __shfl_down(v, 8);
      v += __shfl_down(v, 4);
      v += __shfl_down(v, 2);
      v += __shfl_down(v, 1);
      if (lane == 0) red[wave * 72 + i] = v;
    }
    __syncthreads();   // red ready; also orders all pbuf reads above
                       // before phase 1b's in-place overwrite
    if (tid < 72) {
      float s = red[tid] + red[72 + tid] + red[144 + tid] + red[216 + tid];
      atomicAdd(&kvb[((size_t)b * 16 + gg8) * 72 + tid], s);
    }
    // red is next written only after the 1b->2 barrier, so the tid<72
    // reads above are safely ordered.
  }

  // ---- phase 1b: apply W_p in place (each task owns its 8 LDS slots) ----
  for (int t = tid; t < 3 * NPOS; t += 256) {
    const int gloc = t / NPOS, pos = t % NPOS;
    float qv[8];
#pragma unroll
    for (int i = 0; i < 8; i++) qv[i] = pbuf[(gloc * 8 + i) * NPOS + pos];
    const float* wp = Wp + (size_t)(gg8 * 3 + gloc) * 64;
#pragma unroll
    for (int o = 0; o < 8; o++) {
      float s = 0.f;
#pragma unroll
      for (int i = 0; i < 8; i++) s = fmaf(wp[o * 8 + i], qv[i], s);
      pbuf[(gloc * 8 + o) * NPOS + pos] = s;
    }
  }
  __syncthreads();

  // ---- phase 2: depthwise 3x3, pixel pair (py, px) & (py, px+1) ----
  const float* wdb = Wd + (size_t)gg8 * 24 * 9;
  const int n = (ty0 + py) * NW + (tx0 + px);

  float kk0[8], kk1[8], vv0[8], vv1[8];
#pragma unroll
  for (int cc = 0; cc < 24; ++cc) {
    const float* pb = pbuf + cc * NPOS + py * HALO_W + px;
    const float2 r0a = *(const float2*)(pb);
    const float2 r0b = *(const float2*)(pb + 2);
    const float2 r1a = *(const float2*)(pb + HALO_W);
    const float2 r1b = *(const float2*)(pb + HALO_W + 2);
    const float2 r2a = *(const float2*)(pb + 2 * HALO_W);
    const float2 r2b = *(const float2*)(pb + 2 * HALO_W + 2);
    const float* w = wdb + cc * 9;
    float s0 = 0.f, s1 = 0.f;
    s0 = fmaf(w[0], r0a.x, s0);  s1 = fmaf(w[0], r0a.y, s1);
    s0 = fmaf(w[1], r0a.y, s0);  s1 = fmaf(w[1], r0b.x, s1);
    s0 = fmaf(w[2], r0b.x, s0);  s1 = fmaf(w[2], r0b.y, s1);
    s0 = fmaf(w[3], r1a.x, s0);  s1 = fmaf(w[3], r1a.y, s1);
    s0 = fmaf(w[4], r1a.y, s0);  s1 = fmaf(w[4], r1b.x, s1);
    s0 = fmaf(w[5], r1b.x, s0);  s1 = fmaf(w[5], r1b.y, s1);
    s0 = fmaf(w[6], r2a.x, s0);  s1 = fmaf(w[6], r2a.y, s1);
    s0 = fmaf(w[7], r2a.y, s0);  s1 = fmaf(w[7], r2b.x, s1);
    s0 = fmaf(w[8], r2b.x, s0);  s1 = fmaf(w[8], r2b.y, s1);
    if (cc < 8) {
      float2 o = {fmaxf(s0, 0.f), fmaxf(s1, 0.f)};
      *(float2*)&dq[((size_t)b * 64 + gg8 * 8 + cc) * NHW + n] = o;
    } else if (cc < 16) {
      kk0[cc - 8] = fmaxf(s0, 0.f);
      kk1[cc - 8] = fmaxf(s1, 0.f);
    } else {
      vv0[cc - 16] = s0;
      vv1[cc - 16] = s1;
    }
  }

  float acc[72];
#pragma unroll
  for (int d = 0; d < 8; ++d) {
#pragma unroll
    for (int e = 0; e < 8; ++e)
      acc[d * 9 + e] = fmaf(kk0[d], vv0[e], kk1[d] * vv1[e]);
    acc[d * 9 + 8] = kk0[d] + kk1[d];
  }

#pragma unroll
  for (int i = 0; i < 72; i++) {
    float v = acc[i];
    v += __shfl_down(v, 32);
    v += __shfl_down(v, 16);
    v += __shfl_down(v, 8);
    v += __shfl_down(v, 4);
    v += __shfl_down(v, 2);
    v += __shfl_down(v, 1);
    if (lane == 0) red[wave * 72 + i] = v;
  }
  __syncthreads();
  if (tid < 72) {
    float s = red[tid] + red[72 + tid] + red[144 + tid] + red[216 + tid];
    atomicAdd(&kvb[((size_t)b * 16 + (8 + gg8)) * 72 + tid], s);
  }
}

// ---------------------------------------------------------------------------
// K3: per pixel: q (16 groups x 8) -> o = (q . kv)[:8] / (q . kv)[8]
//     then y = Wffn @ o, BN affine.  (round-3 verified version, unchanged)
// ---------------------------------------------------------------------------
__global__ __launch_bounds__(256) void k3_attn_ffn(
    const float* __restrict__ qkv, const float* __restrict__ dq,
    const float* __restrict__ kvb, const float* __restrict__ Wf,
    const float* __restrict__ gamma, const float* __restrict__ beta,
    const float* __restrict__ mean, const float* __restrict__ var,
    float* __restrict__ out)
{
  __shared__ float wS[64 * 128];        // 32 KB: Wf[m0..m0+63][0..127]
  __shared__ float oS[2][8][256];       // 16 KB: double-buffered o8 per pixel

  const int tid = threadIdx.x;
  const int b   = blockIdx.x >> 6;          // 64 blocks per batch
  const int n0  = (blockIdx.x & 63) << 8;   // 256 pixels per block
  const int m0  = blockIdx.y << 6;          // 64 out-channels per y-tile
  const int tx  = tid & 63;
  const int ty  = tid >> 6;                 // wave id: m-subgroup

  {
    const float* wsrc = Wf + (size_t)m0 * 128;
#pragma unroll
    for (int i = 0; i < 8; ++i) {
      const int off = i * 1024 + tid * 4;
      *(float4*)&wS[off] = *(const float4*)&wsrc[off];
    }
  }

  float acc[16][4];
#pragma unroll
  for (int m = 0; m < 16; ++m)
#pragma unroll
    for (int p = 0; p < 4; ++p) acc[m][p] = 0.f;

  const float* kvB = kvb + (size_t)b * 16 * 72;

  for (int g = 0; g < 16; ++g) {
    // ---- phase A: this thread computes o8 for pixel (n0 + tid) ----
    const float* qp = (g < 8)
        ? qkv + ((size_t)b * NQKV + g * 24) * NHW + n0 + tid
        : dq  + ((size_t)b * 64 + (g - 8) * 8) * NHW + n0 + tid;
    float qv[8];
#pragma unroll
    for (int j = 0; j < 8; ++j) {
      const float v = qp[(size_t)j * NHW];
      qv[j] = (g < 8) ? fmaxf(v, 0.f) : v;
    }
    const float* kvg = kvB + g * 72;   // uniform -> scalar loads
    float num[9];
#pragma unroll
    for (int e = 0; e < 9; ++e) {
      float s = 0.f;
#pragma unroll
      for (int d = 0; d < 8; ++d) s = fmaf(qv[d], kvg[d * 9 + e], s);
      num[e] = s;
    }
    const float r = __builtin_amdgcn_rcpf(num[8] + 1e-15f);
    const int buf = g & 1;
#pragma unroll
    for (int e = 0; e < 8; ++e) oS[buf][e][tid] = num[e] * r;

    __syncthreads();   // oS[buf] ready (also orders next overwrite of buf^1)

    // ---- phase B: 16 m x 4 px FMAs from LDS ----
    float ov[4][8];
#pragma unroll
    for (int p = 0; p < 4; ++p)
#pragma unroll
      for (int e = 0; e < 8; ++e) ov[p][e] = oS[buf][e][tx + p * 64];

    const float* wrow = &wS[(ty * 16) * 128 + g * 8];
#pragma unroll
    for (int m = 0; m < 16; ++m) {
      const float4 w0 = *(const float4*)&wrow[m * 128];
      const float4 w1 = *(const float4*)&wrow[m * 128 + 4];
      const float w8[8] = {w0.x, w0.y, w0.z, w0.w, w1.x, w1.y, w1.z, w1.w};
#pragma unroll
      for (int p = 0; p < 4; ++p)
#pragma unroll
        for (int e = 0; e < 8; ++e)
          acc[m][p] = fmaf(ov[p][e], w8[e], acc[m][p]);
    }
  }

#pragma unroll
  for (int m = 0; m < 16; ++m) {
    const int oc = m0 + ty * 16 + m;
    const float sc = gamma[oc] * __builtin_amdgcn_rsqf(var[oc] + 1e-5f);
    const float bi = fmaf(-mean[oc], sc, beta[oc]);
    float* op = out + ((size_t)b * NCOUT + oc) * NHW + n0 + tx;
#pragma unroll
    for (int p = 0; p < 4; ++p) op[p * 64] = fmaf(acc[m][p], sc, bi);
  }
}

// ---------------------------------------------------------------------------
extern "C" void kernel_launch(void* const* d_in, const int* in_sizes, int n_in,
                              void* d_out, int out_size, void* d_ws, size_t ws_size,
                              hipStream_t stream) {
  const float* x     = (const float*)d_in[0];
  const float* Wq    = (const float*)d_in[1];
  const float* Wp    = (const float*)d_in[2];
  const float* Wd    = (const float*)d_in[3];
  const float* Wf    = (const float*)d_in[4];
  const float* gamma = (const float*)d_in[5];
  const float* beta  = (const float*)d_in[6];
  const float* mean  = (const float*)d_in[7];
  const float* var   = (const float*)d_in[8];
  float* out = (float*)d_out;

  char* ws = (char*)d_ws;
  float* qkv = (float*)ws;                                   // 8*192*16384*4 = 96 MiB
  float* dq  = (float*)(ws + (size_t)100663296);             // 8*64*16384*4  = 32 MiB
  float* kvb = (float*)(ws + (size_t)134217728);             // 8*16*72*4     = 36 KiB

  hipMemsetAsync(kvb, 0, (size_t)NB * 16 * 72 * sizeof(float), stream);

  k1_qkv<<<dim3(1024, 3), 256, 0, stream>>>(x, Wq, qkv);
  k2_dw<<<dim3(256, 8), 256, 0, stream>>>(qkv, Wp, Wd, dq, kvb);
  k3_attn_ffn<<<dim3(512, 4), 256, 0, stream>>>(qkv, dq, kvb, Wf, gamma, beta,
                                                mean, var, out);
}